// Round 2
// baseline (316.584 us; speedup 1.0000x reference)
//
#include <hip/hip_runtime.h>
#include <hip/hip_fp16.h>

#define HH 1080
#define WW 1920
#define NB 8
#define HWP (HH*WW)                 // 2,073,600
#define NPXs ((size_t)NB*HWP)       // 16,588,800
#define NC8 (WW/8)                  // 240 groups of 8 halves

// LDS pad: +1 word every 32 -> stride-8 and stride-32 accesses conflict-free
#define PADI(e) ((e) + ((e) >> 5))

__device__ __forceinline__ int reflH(int y){ int r = y < 0 ? -y : y; return r >= HH ? 2*HH-2-r : r; }
__device__ __forceinline__ int reflW(int x){ int r = x < 0 ? -x : x; return r >= WW ? 2*WW-2-r : r; }

__device__ __forceinline__ unsigned pkmin(unsigned a, unsigned b){
    unsigned r; asm("v_pk_min_f16 %0, %1, %2" : "=v"(r) : "v"(a), "v"(b)); return r;
}
#define INF2 0x7C007C00u

// ---------------------------------------------------------------- K1: dark channel + horizontal erosion
__global__ __launch_bounds__(256) void k_dark_eh(const float* __restrict__ I,
                                                 __half* __restrict__ dark, __half* __restrict__ eh){
    __shared__ float ds[2048];      // PADI(1933)=1993
    int bid = blockIdx.x;
    int y = bid % HH;
    int b = bid / HH;
    const float* row0 = I + (size_t)b*3*HWP + (size_t)y*WW;
    size_t rb = (size_t)b*HWP + (size_t)y*WW;
    int tid = threadIdx.x;
    if (tid < 240){
        int x0 = tid*8;
        float4 c00 = *(const float4*)(row0 + x0);
        float4 c01 = *(const float4*)(row0 + x0 + 4);
        float4 c10 = *(const float4*)(row0 + HWP + x0);
        float4 c11 = *(const float4*)(row0 + HWP + x0 + 4);
        float4 c20 = *(const float4*)(row0 + 2*HWP + x0);
        float4 c21 = *(const float4*)(row0 + 2*HWP + x0 + 4);
        float m[8];
        m[0]=fminf(fminf(c00.x,c10.x),c20.x); m[1]=fminf(fminf(c00.y,c10.y),c20.y);
        m[2]=fminf(fminf(c00.z,c10.z),c20.z); m[3]=fminf(fminf(c00.w,c10.w),c20.w);
        m[4]=fminf(fminf(c01.x,c11.x),c21.x); m[5]=fminf(fminf(c01.y,c11.y),c21.y);
        m[6]=fminf(fminf(c01.z,c11.z),c21.z); m[7]=fminf(fminf(c01.w,c11.w),c21.w);
        __half2 hd[4];
        #pragma unroll
        for (int l=0;l<4;++l) hd[l] = __floats2half2_rn(m[2*l], m[2*l+1]);
        *(uint4*)(dark + rb + x0) = *(uint4*)hd;
        #pragma unroll
        for (int i=0;i<8;++i) ds[PADI(x0+7+i)] = m[i];
    } else if (tid == 240){
        for (int i=0;i<7;++i) ds[PADI(i)] = 1e30f;
    } else if (tid == 241){
        for (int i=0;i<7;++i) ds[PADI(1927+i)] = 1e30f;
    }
    __syncthreads();
    if (tid >= 240) return;
    int x0 = tid*8;
    float s[22];
    #pragma unroll
    for (int i=0;i<22;++i) s[i] = ds[PADI(x0+i)];
    float t1[21], t2[19], t4[15];
    #pragma unroll
    for (int i=0;i<21;++i) t1[i] = fminf(s[i], s[i+1]);
    #pragma unroll
    for (int i=0;i<19;++i) t2[i] = fminf(t1[i], t1[i+2]);
    #pragma unroll
    for (int i=0;i<15;++i) t4[i] = fminf(t2[i], t2[i+4]);
    __half2 ho[4];
    #pragma unroll
    for (int l=0;l<4;++l){
        float o0 = fminf(t4[2*l],   t4[2*l+7]);
        float o1 = fminf(t4[2*l+1], t4[2*l+8]);
        ho[l] = __floats2half2_rn(o0, o1);
    }
    *(uint4*)(eh + rb + x0) = *(uint4*)ho;
}

// ---------------------------------------------------------------- K2: vertical erosion (window 15) via suffix/prefix
__global__ __launch_bounds__(256) void k_erosv(const __half* __restrict__ eh, __half* __restrict__ dim){
    int t = blockIdx.x*256 + threadIdx.x;          // 240*8*72 = 138240 threads, 540 blocks
    int c8 = t % NC8;
    int r  = t / NC8;
    int b  = r & 7;
    int y0 = (r >> 3) * 15;
    const __half* sp = eh  + (size_t)b*HWP + (size_t)c8*8;
    __half*       dp = dim + (size_t)b*HWP + (size_t)c8*8;
    uint4 s[15];
    #pragma unroll
    for (int j=0;j<15;++j){
        int y = y0 - 7 + j;
        if ((unsigned)y < HH) s[j] = *(const uint4*)(sp + (size_t)y*WW);
        else s[j] = make_uint4(INF2,INF2,INF2,INF2);
    }
    #pragma unroll
    for (int j=13;j>=0;--j){
        s[j].x = pkmin(s[j].x, s[j+1].x); s[j].y = pkmin(s[j].y, s[j+1].y);
        s[j].z = pkmin(s[j].z, s[j+1].z); s[j].w = pkmin(s[j].w, s[j+1].w);
    }
    *(uint4*)(dp + (size_t)y0*WW) = s[0];
    uint4 P = make_uint4(INF2,INF2,INF2,INF2);
    #pragma unroll
    for (int j=1;j<15;++j){
        int y = y0 + 7 + j;
        uint4 nv;
        if ((unsigned)y < HH) nv = *(const uint4*)(sp + (size_t)y*WW);
        else nv = make_uint4(INF2,INF2,INF2,INF2);
        P.x = pkmin(P.x, nv.x); P.y = pkmin(P.y, nv.y);
        P.z = pkmin(P.z, nv.z); P.w = pkmin(P.w, nv.w);
        uint4 o;
        o.x = pkmin(s[j].x, P.x); o.y = pkmin(s[j].y, P.y);
        o.z = pkmin(s[j].z, P.z); o.w = pkmin(s[j].w, P.w);
        *(uint4*)(dp + (size_t)(y0+j)*WW) = o;
    }
}

// ---------------------------------------------------------------- K3: vertical box-mean of 4 moments
#define BT 27
__global__ __launch_bounds__(256) void k_blurv4(const __half* __restrict__ dimp, const __half* __restrict__ darkp,
                                                __half* __restrict__ m0, __half* __restrict__ m1,
                                                __half* __restrict__ m2, __half* __restrict__ m3){
    int t = blockIdx.x*256 + threadIdx.x;          // 240*8*40 = 76800 threads, 300 blocks
    int c8 = t % NC8;
    int r  = t / NC8;
    int b  = r & 7;
    int y0 = (r >> 3) * BT;
    size_t base = (size_t)b*HWP + (size_t)c8*8;
    const __half* pd = dimp + base;
    const __half* pk = darkp + base;
    float sI[8], sP[8], sIP[8], sII[8];
    #pragma unroll
    for (int i=0;i<8;++i){ sI[i]=0.f; sP[i]=0.f; sIP[i]=0.f; sII[i]=0.f; }
    auto accA = [&](int yy){
        int yr = reflH(yy);
        uint4 vd = *(const uint4*)(pd + (size_t)yr*WW);
        uint4 vk = *(const uint4*)(pk + (size_t)yr*WW);
        const __half2* hd = (const __half2*)&vd;
        const __half2* hk = (const __half2*)&vk;
        #pragma unroll
        for (int l=0;l<4;++l){
            float2 fd = __half22float2(hd[l]);
            float2 fk = __half22float2(hk[l]);
            sI[2*l]+=fd.x; sI[2*l+1]+=fd.y;
            sP[2*l]+=fk.x; sP[2*l+1]+=fk.y;
            sIP[2*l]+=fd.x*fk.x; sIP[2*l+1]+=fd.y*fk.y;
            sII[2*l]+=fd.x*fd.x; sII[2*l+1]+=fd.y*fd.y;
        }
    };
    auto accS = [&](int yy){
        int yr = reflH(yy);
        uint4 vd = *(const uint4*)(pd + (size_t)yr*WW);
        uint4 vk = *(const uint4*)(pk + (size_t)yr*WW);
        const __half2* hd = (const __half2*)&vd;
        const __half2* hk = (const __half2*)&vk;
        #pragma unroll
        for (int l=0;l<4;++l){
            float2 fd = __half22float2(hd[l]);
            float2 fk = __half22float2(hk[l]);
            sI[2*l]-=fd.x; sI[2*l+1]-=fd.y;
            sP[2*l]-=fk.x; sP[2*l+1]-=fk.y;
            sIP[2*l]-=fd.x*fk.x; sIP[2*l+1]-=fd.y*fk.y;
            sII[2*l]-=fd.x*fd.x; sII[2*l+1]-=fd.y*fd.y;
        }
    };
    const float inv = 1.0f/60.0f;
    for (int k=-29;k<=30;++k) accA(y0+k);
    auto emit = [&](int y){
        size_t off = base + (size_t)y*WW;
        __half2 h[4];
        #pragma unroll
        for (int l=0;l<4;++l) h[l] = __floats2half2_rn(sI[2*l]*inv, sI[2*l+1]*inv);
        *(uint4*)(m0 + off) = *(uint4*)h;
        #pragma unroll
        for (int l=0;l<4;++l) h[l] = __floats2half2_rn(sP[2*l]*inv, sP[2*l+1]*inv);
        *(uint4*)(m1 + off) = *(uint4*)h;
        #pragma unroll
        for (int l=0;l<4;++l) h[l] = __floats2half2_rn(sIP[2*l]*inv, sIP[2*l+1]*inv);
        *(uint4*)(m2 + off) = *(uint4*)h;
        #pragma unroll
        for (int l=0;l<4;++l) h[l] = __floats2half2_rn(sII[2*l]*inv, sII[2*l+1]*inv);
        *(uint4*)(m3 + off) = *(uint4*)h;
    };
    emit(y0);
    for (int y=y0+1; y<y0+BT; ++y){
        accA(y+30);
        accS(y-30);
        emit(y);
    }
}

// ---------------------------------------------------------------- K4: H box-mean of moments + a,b + H box-mean of a,b
__global__ __launch_bounds__(256) void k_hab(const __half* __restrict__ m0, const __half* __restrict__ m1,
                                             const __half* __restrict__ m2, const __half* __restrict__ m3,
                                             __half* __restrict__ aH, __half* __restrict__ bH){
    __shared__ float mom[4][2104];   // e in [0,2038) -> PADI max 2100
    __shared__ float ab[2][2040];    // p in [0,1979) -> PADI max 2039
    int bid = blockIdx.x;
    int y = bid % HH;
    int b = bid / HH;
    size_t rb = (size_t)b*HWP + (size_t)y*WW;
    int tid = threadIdx.x;
    if (tid < 240){
        int x0 = tid*8;
        int e0 = x0 + 58;
        const __half* mp0 = m0 + rb; const __half* mp1 = m1 + rb;
        const __half* mp2 = m2 + rb; const __half* mp3 = m3 + rb;
        uint4 v; const __half2* h = (const __half2*)&v;
        v = *(const uint4*)(mp0 + x0);
        #pragma unroll
        for (int l=0;l<4;++l){ float2 f=__half22float2(h[l]); mom[0][PADI(e0+2*l)]=f.x; mom[0][PADI(e0+2*l+1)]=f.y; }
        v = *(const uint4*)(mp1 + x0);
        #pragma unroll
        for (int l=0;l<4;++l){ float2 f=__half22float2(h[l]); mom[1][PADI(e0+2*l)]=f.x; mom[1][PADI(e0+2*l+1)]=f.y; }
        v = *(const uint4*)(mp2 + x0);
        #pragma unroll
        for (int l=0;l<4;++l){ float2 f=__half22float2(h[l]); mom[2][PADI(e0+2*l)]=f.x; mom[2][PADI(e0+2*l+1)]=f.y; }
        v = *(const uint4*)(mp3 + x0);
        #pragma unroll
        for (int l=0;l<4;++l){ float2 f=__half22float2(h[l]); mom[3][PADI(e0+2*l)]=f.x; mom[3][PADI(e0+2*l+1)]=f.y; }
    } else {
        int h0 = (tid-240)*8;
        for (int i=0;i<8;++i){
            int hh = h0 + i;
            if (hh >= 118) break;
            int e = hh < 58 ? hh : 1978 + (hh-58);
            int x = reflW(e - 58);
            int pe = PADI(e);
            mom[0][pe] = __half2float(m0[rb+x]);
            mom[1][pe] = __half2float(m1[rb+x]);
            mom[2][pe] = __half2float(m2[rb+x]);
            mom[3][pe] = __half2float(m3[rb+x]);
        }
    }
    __syncthreads();
    if (tid < 62){
        int p0 = tid*32;
        int cnt = min(32, 1979 - p0);
        float S0=0,S1=0,S2=0,S3=0;
        for (int k=0;k<60;++k){
            int pe = PADI(p0+k);
            S0 += mom[0][pe]; S1 += mom[1][pe]; S2 += mom[2][pe]; S3 += mom[3][pe];
        }
        const float inv = 1.0f/60.0f;
        for (int j=0;j<cnt;++j){
            if (j){
                int iA = PADI(p0+j+59), iS = PADI(p0+j-1);
                S0 += mom[0][iA]-mom[0][iS]; S1 += mom[1][iA]-mom[1][iS];
                S2 += mom[2][iA]-mom[2][iS]; S3 += mom[3][iA]-mom[3][iS];
            }
            float mI=S0*inv, mP=S1*inv, mIp=S2*inv, mII=S3*inv;
            float cov = mIp - mI*mP;
            float var = mII - mI*mI;
            float a = cov / (var + 1e-4f);
            int pp = PADI(p0+j);
            ab[0][pp] = a;
            ab[1][pp] = mP - a*mI;
        }
    }
    __syncthreads();
    if (tid >= 60) return;
    int x0 = tid*32;
    float sa=0.f, sb=0.f;
    for (int k=0;k<60;++k){
        int pe = PADI(x0+k);
        sa += ab[0][pe]; sb += ab[1][pe];
    }
    const float inv = 1.0f/60.0f;
    __half2 ha[16], hb[16];
    float pa_=0.f, pb_=0.f;
    #pragma unroll
    for (int j=0;j<32;++j){
        if (j){
            int iA = PADI(x0+j+59), iS = PADI(x0+j-1);
            sa += ab[0][iA]-ab[0][iS];
            sb += ab[1][iA]-ab[1][iS];
        }
        float av = sa*inv, bv = sb*inv;
        if (j & 1){
            ha[j>>1] = __floats2half2_rn(pa_, av);
            hb[j>>1] = __floats2half2_rn(pb_, bv);
        } else { pa_ = av; pb_ = bv; }
    }
    *(uint4*)(aH+rb+x0)    = *(uint4*)&ha[0];
    *(uint4*)(aH+rb+x0+8)  = *(uint4*)&ha[4];
    *(uint4*)(aH+rb+x0+16) = *(uint4*)&ha[8];
    *(uint4*)(aH+rb+x0+24) = *(uint4*)&ha[12];
    *(uint4*)(bH+rb+x0)    = *(uint4*)&hb[0];
    *(uint4*)(bH+rb+x0+8)  = *(uint4*)&hb[4];
    *(uint4*)(bH+rb+x0+16) = *(uint4*)&hb[8];
    *(uint4*)(bH+rb+x0+24) = *(uint4*)&hb[12];
}

// ---------------------------------------------------------------- K5: vertical box-mean of aH,bH + q = ma*dim + mb
__global__ __launch_bounds__(256) void k_final(const __half* __restrict__ aHp, const __half* __restrict__ bHp,
                                               const __half* __restrict__ dimp, float* __restrict__ q){
    int t = blockIdx.x*256 + threadIdx.x;          // 240*8*40 = 76800 threads, 300 blocks
    int c8 = t % NC8;
    int r  = t / NC8;
    int b  = r & 7;
    int y0 = (r >> 3) * BT;
    size_t base = (size_t)b*HWP + (size_t)c8*8;
    const __half* pa = aHp + base;
    const __half* pb = bHp + base;
    const __half* pd = dimp + base;
    float* pq = q + base;
    float sa[8], sb[8];
    #pragma unroll
    for (int i=0;i<8;++i){ sa[i]=0.f; sb[i]=0.f; }
    auto accA = [&](int yy){
        int yr = reflH(yy);
        uint4 va = *(const uint4*)(pa + (size_t)yr*WW);
        uint4 vb = *(const uint4*)(pb + (size_t)yr*WW);
        const __half2* hA = (const __half2*)&va;
        const __half2* hB = (const __half2*)&vb;
        #pragma unroll
        for (int l=0;l<4;++l){
            float2 fa = __half22float2(hA[l]);
            float2 fb = __half22float2(hB[l]);
            sa[2*l]+=fa.x; sa[2*l+1]+=fa.y;
            sb[2*l]+=fb.x; sb[2*l+1]+=fb.y;
        }
    };
    auto accS = [&](int yy){
        int yr = reflH(yy);
        uint4 va = *(const uint4*)(pa + (size_t)yr*WW);
        uint4 vb = *(const uint4*)(pb + (size_t)yr*WW);
        const __half2* hA = (const __half2*)&va;
        const __half2* hB = (const __half2*)&vb;
        #pragma unroll
        for (int l=0;l<4;++l){
            float2 fa = __half22float2(hA[l]);
            float2 fb = __half22float2(hB[l]);
            sa[2*l]-=fa.x; sa[2*l+1]-=fa.y;
            sb[2*l]-=fb.x; sb[2*l+1]-=fb.y;
        }
    };
    const float inv = 1.0f/60.0f;
    for (int k=-29;k<=30;++k) accA(y0+k);
    auto emit = [&](int y){
        uint4 vd = *(const uint4*)(pd + (size_t)y*WW);
        const __half2* hd = (const __half2*)&vd;
        float qv[8];
        #pragma unroll
        for (int l=0;l<4;++l){
            float2 fd = __half22float2(hd[l]);
            qv[2*l]   = (sa[2*l]*inv)*fd.x + sb[2*l]*inv;
            qv[2*l+1] = (sa[2*l+1]*inv)*fd.y + sb[2*l+1]*inv;
        }
        float* o = pq + (size_t)y*WW;
        *(float4*)o     = make_float4(qv[0],qv[1],qv[2],qv[3]);
        *(float4*)(o+4) = make_float4(qv[4],qv[5],qv[6],qv[7]);
    };
    emit(y0);
    for (int y=y0+1; y<y0+BT; ++y){
        accA(y+30);
        accS(y-30);
        emit(y);
    }
}

// ---------------------------------------------------------------- launch
extern "C" void kernel_launch(void* const* d_in, const int* in_sizes, int n_in,
                              void* d_out, int out_size, void* d_ws, size_t ws_size,
                              hipStream_t stream){
    const float* I = (const float*)d_in[0];
    float* qout = (float*)d_out;
    __half* ws = (__half*)d_ws;

    __half* p_dark = ws;
    __half* p_eh   = ws + NPXs;
    __half* p_dim  = ws + 2*NPXs;
    __half* p_m0   = ws + 3*NPXs;
    __half* p_m1   = ws + 4*NPXs;
    __half* p_m2   = ws + 5*NPXs;
    __half* p_m3   = ws + 6*NPXs;
    __half* p_aH   = p_dark;   // dark dead after k_blurv4
    __half* p_bH   = p_eh;     // eh dead after k_erosv

    k_dark_eh<<<NB*HH, 256, 0, stream>>>(I, p_dark, p_eh);
    k_erosv  <<<540,   256, 0, stream>>>(p_eh, p_dim);
    k_blurv4 <<<300,   256, 0, stream>>>(p_dim, p_dark, p_m0, p_m1, p_m2, p_m3);
    k_hab    <<<NB*HH, 256, 0, stream>>>(p_m0, p_m1, p_m2, p_m3, p_aH, p_bH);
    k_final  <<<300,   256, 0, stream>>>(p_aH, p_bH, p_dim, qout);
}

// Round 3
// 285.875 us; speedup vs baseline: 1.1074x; 1.1074x over previous
//
#include <hip/hip_runtime.h>
#include <hip/hip_fp16.h>

#define HH 1080
#define WW 1920
#define NB 8
#define HWP (HH*WW)                 // 2,073,600
#define NPXs ((size_t)NB*HWP)       // 16,588,800
#define NC4 (WW/4)                  // 480 groups of 4 halves

// LDS pad for K1: +1 word every 32
#define PADI(e) ((e) + ((e) >> 5))

__device__ __forceinline__ int reflH(int y){ int r = y < 0 ? -y : y; return r >= HH ? 2*HH-2-r : r; }
__device__ __forceinline__ int reflW(int x){ int r = x < 0 ? -x : x; return r >= WW ? 2*WW-2-r : r; }

__device__ __forceinline__ unsigned pkmin(unsigned a, unsigned b){
    unsigned r; asm("v_pk_min_f16 %0, %1, %2" : "=v"(r) : "v"(a), "v"(b)); return r;
}
#define INF2 0x7C007C00u

// ---------------------------------------------------------------- K1: dark channel + horizontal erosion
__global__ __launch_bounds__(256) void k_dark_eh(const float* __restrict__ I,
                                                 __half* __restrict__ dark, __half* __restrict__ eh){
    __shared__ float ds[2048];
    int bid = blockIdx.x;
    int y = bid % HH;
    int b = bid / HH;
    const float* row0 = I + (size_t)b*3*HWP + (size_t)y*WW;
    size_t rb = (size_t)b*HWP + (size_t)y*WW;
    int tid = threadIdx.x;
    if (tid < 240){
        int x0 = tid*8;
        float4 c00 = *(const float4*)(row0 + x0);
        float4 c01 = *(const float4*)(row0 + x0 + 4);
        float4 c10 = *(const float4*)(row0 + HWP + x0);
        float4 c11 = *(const float4*)(row0 + HWP + x0 + 4);
        float4 c20 = *(const float4*)(row0 + 2*HWP + x0);
        float4 c21 = *(const float4*)(row0 + 2*HWP + x0 + 4);
        float m[8];
        m[0]=fminf(fminf(c00.x,c10.x),c20.x); m[1]=fminf(fminf(c00.y,c10.y),c20.y);
        m[2]=fminf(fminf(c00.z,c10.z),c20.z); m[3]=fminf(fminf(c00.w,c10.w),c20.w);
        m[4]=fminf(fminf(c01.x,c11.x),c21.x); m[5]=fminf(fminf(c01.y,c11.y),c21.y);
        m[6]=fminf(fminf(c01.z,c11.z),c21.z); m[7]=fminf(fminf(c01.w,c11.w),c21.w);
        __half2 hd[4];
        #pragma unroll
        for (int l=0;l<4;++l) hd[l] = __floats2half2_rn(m[2*l], m[2*l+1]);
        *(uint4*)(dark + rb + x0) = *(uint4*)hd;
        #pragma unroll
        for (int i=0;i<8;++i) ds[PADI(x0+7+i)] = m[i];
    } else if (tid == 240){
        for (int i=0;i<7;++i) ds[PADI(i)] = 1e30f;
    } else if (tid == 241){
        for (int i=0;i<7;++i) ds[PADI(1927+i)] = 1e30f;
    }
    __syncthreads();
    if (tid >= 240) return;
    int x0 = tid*8;
    float s[22];
    #pragma unroll
    for (int i=0;i<22;++i) s[i] = ds[PADI(x0+i)];
    float t1[21], t2[19], t4[15];
    #pragma unroll
    for (int i=0;i<21;++i) t1[i] = fminf(s[i], s[i+1]);
    #pragma unroll
    for (int i=0;i<19;++i) t2[i] = fminf(t1[i], t1[i+2]);
    #pragma unroll
    for (int i=0;i<15;++i) t4[i] = fminf(t2[i], t2[i+4]);
    __half2 ho[4];
    #pragma unroll
    for (int l=0;l<4;++l){
        float o0 = fminf(t4[2*l],   t4[2*l+7]);
        float o1 = fminf(t4[2*l+1], t4[2*l+8]);
        ho[l] = __floats2half2_rn(o0, o1);
    }
    *(uint4*)(eh + rb + x0) = *(uint4*)ho;
}

// ---------------------------------------------------------------- K2: vertical erosion (window 15) via suffix/prefix
__global__ __launch_bounds__(256) void k_erosv(const __half* __restrict__ eh, __half* __restrict__ dim){
    int t = blockIdx.x*256 + threadIdx.x;          // 480*8*72 threads, 1080 blocks
    int c4 = t % NC4;
    int r  = t / NC4;
    int b  = r & 7;
    int y0 = (r >> 3) * 15;
    const __half* sp = eh  + (size_t)b*HWP + (size_t)c4*4;
    __half*       dp = dim + (size_t)b*HWP + (size_t)c4*4;
    uint2 s[15];
    #pragma unroll
    for (int j=0;j<15;++j){
        int y = y0 - 7 + j;
        if ((unsigned)y < HH) s[j] = *(const uint2*)(sp + (size_t)y*WW);
        else { s[j].x = INF2; s[j].y = INF2; }
    }
    #pragma unroll
    for (int j=13;j>=0;--j){
        s[j].x = pkmin(s[j].x, s[j+1].x); s[j].y = pkmin(s[j].y, s[j+1].y);
    }
    *(uint2*)(dp + (size_t)y0*WW) = s[0];
    uint2 P; P.x = INF2; P.y = INF2;
    #pragma unroll
    for (int j=1;j<15;++j){
        int y = y0 + 7 + j;
        uint2 nv;
        if ((unsigned)y < HH) nv = *(const uint2*)(sp + (size_t)y*WW);
        else { nv.x = INF2; nv.y = INF2; }
        P.x = pkmin(P.x, nv.x); P.y = pkmin(P.y, nv.y);
        uint2 o;
        o.x = pkmin(s[j].x, P.x); o.y = pkmin(s[j].y, P.y);
        *(uint2*)(dp + (size_t)(y0+j)*WW) = o;
    }
}

// ---------------------------------------------------------------- K3: vertical box-mean of 4 moments
#define BT 18
__global__ __launch_bounds__(256) void k_blurv4(const __half* __restrict__ dimp, const __half* __restrict__ darkp,
                                                __half* __restrict__ m0, __half* __restrict__ m1,
                                                __half* __restrict__ m2, __half* __restrict__ m3){
    int t = blockIdx.x*256 + threadIdx.x;          // 480*8*60 threads, 900 blocks
    int c4 = t % NC4;
    int r  = t / NC4;
    int b  = r & 7;
    int y0 = (r >> 3) * BT;
    size_t base = (size_t)b*HWP + (size_t)c4*4;
    const __half* pd = dimp + base;
    const __half* pk = darkp + base;
    float sI[4], sP[4], sIP[4], sII[4];
    #pragma unroll
    for (int i=0;i<4;++i){ sI[i]=0.f; sP[i]=0.f; sIP[i]=0.f; sII[i]=0.f; }
    auto accA = [&](int yy){
        int yr = reflH(yy);
        uint2 vd = *(const uint2*)(pd + (size_t)yr*WW);
        uint2 vk = *(const uint2*)(pk + (size_t)yr*WW);
        const __half2* hd = (const __half2*)&vd;
        const __half2* hk = (const __half2*)&vk;
        #pragma unroll
        for (int l=0;l<2;++l){
            float2 fd = __half22float2(hd[l]);
            float2 fk = __half22float2(hk[l]);
            sI[2*l]+=fd.x; sI[2*l+1]+=fd.y;
            sP[2*l]+=fk.x; sP[2*l+1]+=fk.y;
            sIP[2*l]+=fd.x*fk.x; sIP[2*l+1]+=fd.y*fk.y;
            sII[2*l]+=fd.x*fd.x; sII[2*l+1]+=fd.y*fd.y;
        }
    };
    auto accS = [&](int yy){
        int yr = reflH(yy);
        uint2 vd = *(const uint2*)(pd + (size_t)yr*WW);
        uint2 vk = *(const uint2*)(pk + (size_t)yr*WW);
        const __half2* hd = (const __half2*)&vd;
        const __half2* hk = (const __half2*)&vk;
        #pragma unroll
        for (int l=0;l<2;++l){
            float2 fd = __half22float2(hd[l]);
            float2 fk = __half22float2(hk[l]);
            sI[2*l]-=fd.x; sI[2*l+1]-=fd.y;
            sP[2*l]-=fk.x; sP[2*l+1]-=fk.y;
            sIP[2*l]-=fd.x*fk.x; sIP[2*l+1]-=fd.y*fk.y;
            sII[2*l]-=fd.x*fd.x; sII[2*l+1]-=fd.y*fd.y;
        }
    };
    const float inv = 1.0f/60.0f;
    for (int k=-29;k<=30;++k) accA(y0+k);
    auto emit = [&](int y){
        size_t off = base + (size_t)y*WW;
        __half2 h[2];
        h[0]=__floats2half2_rn(sI[0]*inv,sI[1]*inv);  h[1]=__floats2half2_rn(sI[2]*inv,sI[3]*inv);
        *(uint2*)(m0+off) = *(uint2*)h;
        h[0]=__floats2half2_rn(sP[0]*inv,sP[1]*inv);  h[1]=__floats2half2_rn(sP[2]*inv,sP[3]*inv);
        *(uint2*)(m1+off) = *(uint2*)h;
        h[0]=__floats2half2_rn(sIP[0]*inv,sIP[1]*inv); h[1]=__floats2half2_rn(sIP[2]*inv,sIP[3]*inv);
        *(uint2*)(m2+off) = *(uint2*)h;
        h[0]=__floats2half2_rn(sII[0]*inv,sII[1]*inv); h[1]=__floats2half2_rn(sII[2]*inv,sII[3]*inv);
        *(uint2*)(m3+off) = *(uint2*)h;
    };
    emit(y0);
    for (int y=y0+1; y<y0+BT; ++y){
        accA(y+30);
        accS(y-30);
        emit(y);
    }
}

// ---------------------------------------------------------------- K4: H-blur(moments) + a,b + H-blur(a,b) via prefix scans
// Padded seq: xp[j] = m[reflW(j-29)], j=0..1978. out[x] = sum_{j=x..x+59} xp[j].
// Scan index s = j+3 (zeros for s<3, s>1981). Thread u owns s=8u..8u+7.
// PiS[z] = Pi[z+2] (inclusive prefix), stored de-interleaved: chunk c=z>>2,
//   c even -> PA[c>>1], c odd -> PB[c>>1]. out[x] = PiS[x+60]-PiS[x].
// Second blur over x-grid with reflect corrections, PrS[z] holds Pr[z-30].
__global__ __launch_bounds__(256) void k_hab(const __half* __restrict__ m0, const __half* __restrict__ m1,
                                             const __half* __restrict__ m2, const __half* __restrict__ m3,
                                             __half* __restrict__ aH, __half* __restrict__ bH){
    __shared__ float4 PA[4][256];
    __shared__ float4 PB[4][256];
    __shared__ float4 QA[2][264];
    __shared__ float4 QB[2][264];
    __shared__ float wt[4][4];
    __shared__ float wt2[2][4];

    int bid = blockIdx.x;
    int y = bid % HH;
    int b = bid / HH;
    size_t rb = (size_t)b*HWP + (size_t)y*WW;
    int tid = threadIdx.x;
    int lane = tid & 63;
    int wv = tid >> 6;

    const __half* mp0 = m0 + rb; const __half* mp1 = m1 + rb;
    const __half* mp2 = m2 + rb; const __half* mp3 = m3 + rb;

    // ---- scan-input loads
    float xv[4][8];
    int u = tid;
    if (u >= 4 && u <= 243){
        int x0 = 8*(u-4);
        const __half* mp[4] = {mp0, mp1, mp2, mp3};
        #pragma unroll
        for (int p=0;p<4;++p){
            uint4 hv = *(const uint4*)(mp[p] + x0);
            const __half2* h2 = (const __half2*)&hv;
            #pragma unroll
            for (int l=0;l<4;++l){
                float2 f = __half22float2(h2[l]);
                xv[p][2*l] = f.x; xv[p][2*l+1] = f.y;
            }
        }
    } else {
        #pragma unroll
        for (int i=0;i<8;++i){
            int s = 8*u + i;
            if (s >= 3 && s <= 1981){
                int j = s - 3;
                int x = j - 29;
                if (x < 0) x = -x;
                else if (x > 1919) x = 3838 - x;
                xv[0][i] = __half2float(mp0[x]);
                xv[1][i] = __half2float(mp1[x]);
                xv[2][i] = __half2float(mp2[x]);
                xv[3][i] = __half2float(mp3[x]);
            } else {
                xv[0][i]=0.f; xv[1][i]=0.f; xv[2][i]=0.f; xv[3][i]=0.f;
            }
        }
    }

    // ---- local prefix + wave scan
    float ebase[4];
    #pragma unroll
    for (int p=0;p<4;++p){
        #pragma unroll
        for (int i=1;i<8;++i) xv[p][i] += xv[p][i-1];
        float v = xv[p][7];
        #pragma unroll
        for (int d=1; d<64; d<<=1){
            float tmp = __shfl_up(v, d);
            if (lane >= d) v += tmp;
        }
        ebase[p] = v - xv[p][7];
        if (lane == 63) wt[p][wv] = v;
    }
    __syncthreads();
    #pragma unroll
    for (int p=0;p<4;++p){
        float bb = ebase[p];
        if (wv > 0) bb += wt[p][0];
        if (wv > 1) bb += wt[p][1];
        if (wv > 2) bb += wt[p][2];
        #pragma unroll
        for (int i=0;i<8;++i) xv[p][i] += bb;   // xv[p][i] = Pi[8u+i]
        if (u > 0) *((float2*)&PB[p][u-1] + 1) = make_float2(xv[p][0], xv[p][1]);
        PA[p][u] = make_float4(xv[p][2], xv[p][3], xv[p][4], xv[p][5]);
        *((float2*)&PB[p][u]) = make_float2(xv[p][6], xv[p][7]);
    }
    __syncthreads();

    // ---- phase 3a: window means + a,b
    float Aa[8], Bb[8];
    int t = tid;
    if (t < 240){
        const float inv = 1.0f/60.0f;
        float mm[4][8];
        #pragma unroll
        for (int p=0;p<4;++p){
            float4 loa = PA[p][t];
            float4 lob = PB[p][t];
            float4 hib = PB[p][t+7];
            float4 hia = PA[p][t+8];
            mm[p][0]=(hib.x-loa.x)*inv; mm[p][1]=(hib.y-loa.y)*inv;
            mm[p][2]=(hib.z-loa.z)*inv; mm[p][3]=(hib.w-loa.w)*inv;
            mm[p][4]=(hia.x-lob.x)*inv; mm[p][5]=(hia.y-lob.y)*inv;
            mm[p][6]=(hia.z-lob.z)*inv; mm[p][7]=(hia.w-lob.w)*inv;
        }
        #pragma unroll
        for (int i=0;i<8;++i){
            float mI=mm[0][i], mP=mm[1][i], mIp=mm[2][i], mII=mm[3][i];
            float cov = mIp - mI*mP;
            float var = mII - mI*mI;
            float a = cov / (var + 1e-4f);
            Aa[i] = a;
            Bb[i] = mP - a*mI;
        }
    } else {
        #pragma unroll
        for (int i=0;i<8;++i){ Aa[i]=0.f; Bb[i]=0.f; }
    }

    // ---- scan2 over a and b (x-grid, 1920 values in threads 0..239)
    float eA, eB;
    {
        #pragma unroll
        for (int i=1;i<8;++i) Aa[i] += Aa[i-1];
        float v = Aa[7];
        #pragma unroll
        for (int d=1; d<64; d<<=1){
            float tmp = __shfl_up(v, d);
            if (lane >= d) v += tmp;
        }
        eA = v - Aa[7];
        if (lane==63) wt2[0][wv] = v;
    }
    {
        #pragma unroll
        for (int i=1;i<8;++i) Bb[i] += Bb[i-1];
        float v = Bb[7];
        #pragma unroll
        for (int d=1; d<64; d<<=1){
            float tmp = __shfl_up(v, d);
            if (lane >= d) v += tmp;
        }
        eB = v - Bb[7];
        if (lane==63) wt2[1][wv] = v;
    }
    __syncthreads();
    {
        float bb = eA;
        if (wv>0) bb += wt2[0][0];
        if (wv>1) bb += wt2[0][1];
        if (wv>2) bb += wt2[0][2];
        #pragma unroll
        for (int i=0;i<8;++i) Aa[i] += bb;      // Aa[i] = Pr_a[8t+i]
        bb = eB;
        if (wv>0) bb += wt2[1][0];
        if (wv>1) bb += wt2[1][1];
        if (wv>2) bb += wt2[1][2];
        #pragma unroll
        for (int i=0;i<8;++i) Bb[i] += bb;
    }
    // PrS writes: cells z=8t+30..8t+37 hold Pr[8t..8t+7]
    *((float2*)&QB[0][t+3] + 1) = make_float2(Aa[0], Aa[1]);
    QA[0][t+4] = make_float4(Aa[2], Aa[3], Aa[4], Aa[5]);
    *((float2*)&QB[0][t+4]) = make_float2(Aa[6], Aa[7]);
    *((float2*)&QB[1][t+3] + 1) = make_float2(Bb[0], Bb[1]);
    QA[1][t+4] = make_float4(Bb[2], Bb[3], Bb[4], Bb[5]);
    *((float2*)&QB[1][t+4]) = make_float2(Bb[6], Bb[7]);
    if (tid >= 248){
        int k = tid - 248;
        float4 z4 = make_float4(0.f,0.f,0.f,0.f);
        if (k < 4){ QA[0][k] = z4; QA[1][k] = z4; }
        else if (k < 7){ QB[0][k-4] = z4; QB[1][k-4] = z4; }
        else { *((float2*)&QB[0][3]) = make_float2(0.f,0.f);
               *((float2*)&QB[1][3]) = make_float2(0.f,0.f); }
    }
    __syncthreads();
    if (t >= 240) return;

    // ---- phase 3c: second blur outputs
    int x0 = 8*t;
    float4 lA0 = QA[0][t];   float4 lA1 = QB[0][t];
    float4 hA0 = QB[0][t+7]; float4 hA1 = QA[0][t+8];
    float4 lB0 = QA[1][t];   float4 lB1 = QB[1][t];
    float4 hB0 = QB[1][t+7]; float4 hB1 = QA[1][t+8];
    float sA[8], sB[8];
    sA[0]=hA0.x-lA0.x; sA[1]=hA0.y-lA0.y; sA[2]=hA0.z-lA0.z; sA[3]=hA0.w-lA0.w;
    sA[4]=hA1.x-lA1.x; sA[5]=hA1.y-lA1.y; sA[6]=hA1.z-lA1.z; sA[7]=hA1.w-lA1.w;
    sB[0]=hB0.x-lB0.x; sB[1]=hB0.y-lB0.y; sB[2]=hB0.z-lB0.z; sB[3]=hB0.w-lB0.w;
    sB[4]=hB1.x-lB1.x; sB[5]=hB1.y-lB1.y; sB[6]=hB1.z-lB1.z; sB[7]=hB1.w-lB1.w;

    auto prRead = [&](int pl, int v)->float{
        int z = v + 30;
        int c = z >> 2;
        float4 f = (c & 1) ? QB[pl][c>>1] : QA[pl][c>>1];
        int w = z & 3;
        return (w==0)?f.x:((w==1)?f.y:((w==2)?f.z:f.w));
    };
    if (x0 < 29){
        #pragma unroll
        for (int i=0;i<8;++i){
            int x = x0 + i;
            if (x < 29){
                sA[i] += prRead(0, 29-x) - prRead(0, 0);
                sB[i] += prRead(1, 29-x) - prRead(1, 0);
            }
        }
    }
    if (x0 + 7 > 1889){
        #pragma unroll
        for (int i=0;i<8;++i){
            int x = x0 + i;
            if (x > 1889){
                sA[i] += prRead(0, 1918) - prRead(0, 3807-x);
                sB[i] += prRead(1, 1918) - prRead(1, 3807-x);
            }
        }
    }
    const float inv = 1.0f/60.0f;
    __half2 ha[4], hb[4];
    #pragma unroll
    for (int l=0;l<4;++l){
        ha[l] = __floats2half2_rn(sA[2*l]*inv, sA[2*l+1]*inv);
        hb[l] = __floats2half2_rn(sB[2*l]*inv, sB[2*l+1]*inv);
    }
    *(uint4*)(aH + rb + x0) = *(uint4*)ha;
    *(uint4*)(bH + rb + x0) = *(uint4*)hb;
}

// ---------------------------------------------------------------- K5: vertical box-mean of aH,bH + q
__global__ __launch_bounds__(256) void k_final(const __half* __restrict__ aHp, const __half* __restrict__ bHp,
                                               const __half* __restrict__ dimp, float* __restrict__ q){
    int t = blockIdx.x*256 + threadIdx.x;          // 480*8*60 threads, 900 blocks
    int c4 = t % NC4;
    int r  = t / NC4;
    int b  = r & 7;
    int y0 = (r >> 3) * BT;
    size_t base = (size_t)b*HWP + (size_t)c4*4;
    const __half* pa = aHp + base;
    const __half* pb = bHp + base;
    const __half* pd = dimp + base;
    float* pq = q + base;
    float sa[4], sb[4];
    #pragma unroll
    for (int i=0;i<4;++i){ sa[i]=0.f; sb[i]=0.f; }
    auto accA = [&](int yy){
        int yr = reflH(yy);
        uint2 va = *(const uint2*)(pa + (size_t)yr*WW);
        uint2 vb = *(const uint2*)(pb + (size_t)yr*WW);
        const __half2* hA = (const __half2*)&va;
        const __half2* hB = (const __half2*)&vb;
        #pragma unroll
        for (int l=0;l<2;++l){
            float2 fa = __half22float2(hA[l]);
            float2 fb = __half22float2(hB[l]);
            sa[2*l]+=fa.x; sa[2*l+1]+=fa.y;
            sb[2*l]+=fb.x; sb[2*l+1]+=fb.y;
        }
    };
    auto accS = [&](int yy){
        int yr = reflH(yy);
        uint2 va = *(const uint2*)(pa + (size_t)yr*WW);
        uint2 vb = *(const uint2*)(pb + (size_t)yr*WW);
        const __half2* hA = (const __half2*)&va;
        const __half2* hB = (const __half2*)&vb;
        #pragma unroll
        for (int l=0;l<2;++l){
            float2 fa = __half22float2(hA[l]);
            float2 fb = __half22float2(hB[l]);
            sa[2*l]-=fa.x; sa[2*l+1]-=fa.y;
            sb[2*l]-=fb.x; sb[2*l+1]-=fb.y;
        }
    };
    const float inv = 1.0f/60.0f;
    for (int k=-29;k<=30;++k) accA(y0+k);
    auto emit = [&](int y){
        uint2 vd = *(const uint2*)(pd + (size_t)y*WW);
        const __half2* hd = (const __half2*)&vd;
        float2 f0 = __half22float2(hd[0]);
        float2 f1 = __half22float2(hd[1]);
        float4 o;
        o.x = (sa[0]*inv)*f0.x + sb[0]*inv;
        o.y = (sa[1]*inv)*f0.y + sb[1]*inv;
        o.z = (sa[2]*inv)*f1.x + sb[2]*inv;
        o.w = (sa[3]*inv)*f1.y + sb[3]*inv;
        *(float4*)(pq + (size_t)y*WW) = o;
    };
    emit(y0);
    for (int y=y0+1; y<y0+BT; ++y){
        accA(y+30);
        accS(y-30);
        emit(y);
    }
}

// ---------------------------------------------------------------- launch
extern "C" void kernel_launch(void* const* d_in, const int* in_sizes, int n_in,
                              void* d_out, int out_size, void* d_ws, size_t ws_size,
                              hipStream_t stream){
    const float* I = (const float*)d_in[0];
    float* qout = (float*)d_out;
    __half* ws = (__half*)d_ws;

    __half* p_dark = ws;
    __half* p_eh   = ws + NPXs;
    __half* p_dim  = ws + 2*NPXs;
    __half* p_m0   = ws + 3*NPXs;
    __half* p_m1   = ws + 4*NPXs;
    __half* p_m2   = ws + 5*NPXs;
    __half* p_m3   = ws + 6*NPXs;
    __half* p_aH   = p_dark;   // dark dead after k_blurv4
    __half* p_bH   = p_eh;     // eh dead after k_erosv

    k_dark_eh<<<NB*HH, 256, 0, stream>>>(I, p_dark, p_eh);
    k_erosv  <<<1080,  256, 0, stream>>>(p_eh, p_dim);
    k_blurv4 <<<900,   256, 0, stream>>>(p_dim, p_dark, p_m0, p_m1, p_m2, p_m3);
    k_hab    <<<NB*HH, 256, 0, stream>>>(p_m0, p_m1, p_m2, p_m3, p_aH, p_bH);
    k_final  <<<900,   256, 0, stream>>>(p_aH, p_bH, p_dim, qout);
}